// Round 5
// baseline (89.136 us; speedup 1.0000x reference)
//
#include <hip/hip_runtime.h>
#include <hip/hip_bf16.h>

// Problem constants: B=128, C=21, L=2048, W=32, S=8, O=16, NW=252, NK=4032, K=672
#define Cc   21
#define Ll   2048
#define Oo   16
#define NWw  252
#define NKk  4032
#define Kk   672
#define KP   680   // LDS pitch (bf16) per o-row: conflict-light b128

typedef __attribute__((ext_vector_type(8))) short  short8;  // 8 bf16 = 4 VGPRs
typedef __attribute__((ext_vector_type(4))) float  f32x4;

static __device__ __forceinline__ unsigned short f2bf(float f) {
    union { __hip_bfloat16 h; unsigned short u; } cv;
    cv.h = __float2bfloat16(f);
    return cv.u;
}

static __device__ __forceinline__ short8 cvt8(const float4 a0, const float4 a1) {
    short8 a;
    a[0] = (short)f2bf(a0.x); a[1] = (short)f2bf(a0.y);
    a[2] = (short)f2bf(a0.z); a[3] = (short)f2bf(a0.w);
    a[4] = (short)f2bf(a1.x); a[5] = (short)f2bf(a1.y);
    a[6] = (short)f2bf(a1.z); a[7] = (short)f2bf(a1.w);
    return a;
}

// R16: DIAGNOSTIC round. Four theories died on inferred counters (R12 NT,
// R14 reuse/granularity, R15 warm; only R13 issue-batching moved −3);
// fb_fwd has never been visible in the top-5 (44 us harness fills crowd
// it). This round: SAME total work/math/output, but grid 128 with each
// block serially computing both bq-halves of its group -> one ~50 us
// dispatch that surfaces FETCH_SIZE / VALUBusy / MfmaUtil / Occupancy.
// Interpretation matrix precommitted in the journal:
//   FETCH >~70MB -> over-fetch real; ~35-45MB + low VALU -> latency floor
//   -> global_load_lds restructure; raw VALUBusy >=25% -> VALU/issue-bound
//   -> trim cvt; per-unit <<23us -> stampede breadth was the cost.
// Structure per unit = R14 (verified): group g = 4 windows x 32 batches,
// w staged once fp32->bf16 to LDS (batched 11+10), whole A-slice batch-
// issued, 21-MFMA sweep, NT stores. Blocks: r=bid&7 (XCD), i2=bid>>3:
// g = r*8 + (i2>>1), bq = (i2&1)*2 + pass. 2 idle blocks (g=63).
__global__ __launch_bounds__(512)
void fb_fwd(const float* __restrict__ x, const float* __restrict__ w,
            float* __restrict__ out) {
    __shared__ unsigned short ws[4 * Oo * KP];   // 87.0 KB

    const int bid = blockIdx.x;
    const int r   = bid & 7;            // XCD (round-robin assumption)
    const int i2  = bid >> 3;           // 0..15
    const int g   = r * 8 + (i2 >> 1);  // window group (4 windows)
    if (g > 62) return;
    const int bq0  = (i2 & 1) * 2;      // batch quarters {bq0, bq0+1}
    const int tid  = threadIdx.x;
    const int lane = tid & 63;
    const int wv   = tid >> 6;          // 0..7
    const int wm   = wv >> 2;           // m-tile within pass (0..1)
    const int ww   = wv & 3;            // window within group
    const int col  = lane & 15;         // MFMA m-row (A) / n-col (B = o)
    const int quad = lane >> 4;         // k-chunk selector
    const int j    = g * 4 + ww;        // global window id
    const int s_loc = (j < NWw - 1) ? ww * 8 : 32;  // j=251: start 2016

    // ---- stage w for the 4 windows: 10752 float4, batched 11+10 ----
    const f32x4* wj4 = (const f32x4*)w + (size_t)g * 10752;
    f32x4 wb[11];
#pragma unroll
    for (int p = 0; p < 11; ++p) wb[p] = wj4[tid + p * 512];
#pragma unroll
    for (int p = 0; p < 11; ++p) {
        int t  = tid + p * 512;
        int oa = t / 168;               // (window,o) pair: 0..63
        int r4 = t - oa * 168;
        *(ushort4*)&ws[oa * KP + r4 * 4] =
            make_ushort4(f2bf(wb[p][0]), f2bf(wb[p][1]),
                         f2bf(wb[p][2]), f2bf(wb[p][3]));
    }
#pragma unroll
    for (int p = 0; p < 10; ++p) wb[p] = wj4[tid + (11 + p) * 512];
#pragma unroll
    for (int p = 0; p < 10; ++p) {
        int t  = tid + (11 + p) * 512;
        int oa = t / 168;
        int r4 = t - oa * 168;
        *(ushort4*)&ws[oa * KP + r4 * 4] =
            make_ushort4(f2bf(wb[p][0]), f2bf(wb[p][1]),
                         f2bf(wb[p][2]), f2bf(wb[p][3]));
    }
    __syncthreads();

    const unsigned short* wrow = &ws[(ww * Oo + col) * KP + quad * 8];

    // ---- two serial passes: bq = bq0, bq0+1 (all units computed once) ----
#pragma unroll
    for (int pp = 0; pp < 2; ++pp) {
        const int bq = bq0 + pp;
        const int b  = bq * 32 + wm * 16 + col;
        const float* xrow = x + ((size_t)b * Cc) * Ll + g * 32 + s_loc + quad * 8;
        float4 a0[Cc], a1[Cc];
#pragma unroll
        for (int c = 0; c < Cc; ++c) {
            a0[c] = *(const float4*)(xrow + (size_t)c * Ll);
            a1[c] = *(const float4*)(xrow + (size_t)c * Ll + 4);
        }
        f32x4 acc = {0.f, 0.f, 0.f, 0.f};
#pragma unroll
        for (int c = 0; c < Cc; ++c) {
            short8 afr = cvt8(a0[c], a1[c]);
            acc = __builtin_amdgcn_mfma_f32_16x16x32_bf16(
                afr, *(const short8*)(wrow + c * 32), acc, 0, 0, 0);
        }
        // C/D layout: col = lane&15, row = quad*4 + reg (verified)
        const int rbase = bq * 32 + wm * 16 + quad * 4;
        float* op = out + (size_t)rbase * NKk + j * 16 + col;
#pragma unroll
        for (int rr = 0; rr < 4; ++rr)
            __builtin_nontemporal_store(acc[rr], &op[(size_t)rr * NKk]);
    }
}

extern "C" void kernel_launch(void* const* d_in, const int* in_sizes, int n_in,
                              void* d_out, int out_size, void* d_ws, size_t ws_size,
                              hipStream_t stream) {
    const float* x = (const float*)d_in[0];   // (128, 21, 2048) fp32
    const float* w = (const float*)d_in[1];   // (4032, 672) fp32
    float* out = (float*)d_out;               // (128, 4032) fp32
    fb_fwd<<<dim3(128), dim3(512), 0, stream>>>(x, w, out);
}